// Round 9
// baseline (215.252 us; speedup 1.0000x reference)
//
#include <hip/hip_runtime.h>
#include <stdint.h>

typedef unsigned short u16;
typedef __bf16 bf16x8 __attribute__((ext_vector_type(8)));
typedef float f32x4 __attribute__((ext_vector_type(4)));

#define S_LEN 2048
#define NH    16
#define DM    1024
#define N3    3072
#define MROWS 4096   // B*S

// ---------- scalar bf16 helpers ----------
__device__ __forceinline__ float b2f(u16 u) {
  unsigned int v = ((unsigned int)u) << 16;
  return __builtin_bit_cast(float, v);
}
__device__ __forceinline__ u16 f2b(float f) {
  unsigned int v = __builtin_bit_cast(unsigned int, f);
  v += 0x7fffu + ((v >> 16) & 1u);   // RNE
  return (u16)(v >> 16);
}
__device__ __forceinline__ u16 f2b_trunc(float f) {
  return (u16)(__builtin_bit_cast(unsigned int, f) >> 16);
}
__device__ __forceinline__ bf16x8 ld8(const u16* p) { return *(const bf16x8*)p; }
__device__ __forceinline__ f32x4 mfma16(bf16x8 a, bf16x8 b, f32x4 c) {
  return __builtin_amdgcn_mfma_f32_16x16x32_bf16(a, b, c, 0, 0, 0);
}
__device__ __forceinline__ void glds16(const void* g, void* l) {
  __builtin_amdgcn_global_load_lds(
      (const __attribute__((address_space(1))) unsigned int*)g,
      (__attribute__((address_space(3))) unsigned int*)l, 16, 0, 0);
}
// bf16-vs-f32 word test: low-16 as bf16, exponent in [100,134]
__device__ __forceinline__ int bfish(unsigned int w) {
  unsigned int e = (w >> 7) & 0xffu;
  return (e >= 100u && e <= 134u) ? 1 : 0;
}

// ---------- fused prep: x->bf16 + cs table + both weight transposes + flag ----------
// blocks [0,2048): x conv | [2048,2560): cs table | [2560,3328): wqkv^T | [3328,3584): wout^T
__global__ __launch_bounds__(256) void prep_kernel(const void* __restrict__ x,
                                                   const void* __restrict__ wqkv,
                                                   const void* __restrict__ wout,
                                                   u16* __restrict__ xb,
                                                   u16* __restrict__ wqT,
                                                   u16* __restrict__ woT,
                                                   float* __restrict__ cs,
                                                   int* __restrict__ flag) {
  const int bx = blockIdx.x;
  const int t = threadIdx.x;
  if (bx < 2048) {                       // x -> bf16, self-detecting
    __shared__ int cnt;
    if (t == 0) cnt = 0;
    __syncthreads();
    size_t i = (size_t)bx * 256 + t;     // 524288 uint4 slots (safe both dtypes)
    const uint4* xv = (const uint4*)x;
    uint4 probe = xv[i];
    unsigned int wds[4]; *(uint4*)wds = probe;
    atomicAdd(&cnt, bfish(wds[0]) + bfish(wds[1]) + bfish(wds[2]) + bfish(wds[3]));
    __syncthreads();
    const int isbf = cnt > 512;
    if (t == 0) *flag = isbf;            // benign same-value race
    if (isbf) {
      ((uint4*)xb)[i] = probe;
    } else {
      const float* xf = (const float*)x;
      #pragma unroll
      for (int j = 0; j < 8; ++j) xb[i * 8 + j] = f2b(xf[i * 8 + j]);
    }
    return;
  }
  if (bx < 2560) {                       // cs table: [64 d][2048 s] interleaved (cos,sin)
    int i = (bx - 2048) * 256 + t;       // 131072 = 64*2048
    int d = i >> 11, s = i & 2047;
    int f = d & 31;                      // concat(freqs,freqs): inv_freq index = d mod 32
    float invf = expf(-(float)(2 * f) * (1.0f / 64.0f) * logf(10000.0f));
    float th = (float)s * invf;
    float sv, cv;
    sincosf(th, &sv, &cv);
    cs[i * 2] = cv; cs[i * 2 + 1] = sv;  // i*2 == (d*2048+s)*2
    return;
  }
  // weight transpose [R=1024][C] -> bf16 [C][1024], 64x64 tiles (V-transpose pattern)
  const int wq = bx < 3328;
  const int id = wq ? (bx - 2560) : (bx - 3328);
  const int ncx = wq ? 48 : 16;
  const void* in = wq ? wqkv : wout;
  u16* out = wq ? wqT : woT;
  const int C = wq ? 3072 : 1024;
  const int c0 = (id % ncx) * 64, r0 = (id / ncx) * 64;
  __shared__ int cnt;
  __shared__ u16 L[4096];                // [64 c][64 r], r-seg XOR swizzled
  if (t == 0) cnt = 0;
  __syncthreads();
  const unsigned int* wv = (const unsigned int*)in;
  size_t off = (((size_t)id) * 256 + t) & 262143;   // sample first 256K words (safe both)
  atomicAdd(&cnt, bfish(wv[off]));
  __syncthreads();
  const int fl = cnt > 128;
  if (fl) {                              // bf16: uint4 loads, unpack into swizzled LDS
    #pragma unroll
    for (int it = 0; it < 2; ++it) {
      int c = it * 256 + t;
      int rl = c >> 3, cseg = c & 7;
      uint4 v = *(const uint4*)((const u16*)in + (size_t)(r0 + rl) * C + c0 + cseg * 8);
      u16 e[8]; *(uint4*)e = v;
      #pragma unroll
      for (int jj = 0; jj < 8; ++jj) {
        int cl = cseg * 8 + jj;
        L[cl * 64 + (rl ^ (cseg << 3))] = e[jj];
      }
    }
  } else {                               // fp32 fallback: scalar convert
    const float* inf_ = (const float*)in;
    #pragma unroll
    for (int it = 0; it < 16; ++it) {
      int c = it * 256 + t;
      int rl = c >> 6, cl = c & 63;
      L[cl * 64 + (rl ^ ((cl >> 3) << 3))] = f2b(inf_[(size_t)(r0 + rl) * C + c0 + cl]);
    }
  }
  __syncthreads();
  #pragma unroll
  for (int it = 0; it < 2; ++it) {
    int c = it * 256 + t;
    int cl = c >> 3, rseg = c & 7;
    uint4 v = *(const uint4*)(L + cl * 64 + (((rseg ^ (cl >> 3)) & 7) << 3));
    *(uint4*)(out + (size_t)(c0 + cl) * 1024 + r0 + rseg * 8) = v;
  }
}

// ---------- QKV GEMM 128x128, BK=64: A direct->regs, B glds->LDS; fused RoPE/V^T ----------
// A: xb [4096][1024], Bt: wqT [3072][1024]
// Q,K -> [bh][2048][64] (Q pre-scaled by log2e/8); V -> Vt [bh][64][2048]
__global__ __launch_bounds__(256) void gemm_qkv(const u16* __restrict__ A,
                                                const u16* __restrict__ Bt,
                                                u16* __restrict__ Qo,
                                                u16* __restrict__ Ko,
                                                u16* __restrict__ Vt,
                                                const float* __restrict__ cs) {
  __shared__ u16 Bl[8192];             // [128][64] = 16 KB
  const int t = threadIdx.x;
  const int lane = t & 63, wave = t >> 6;
  const int ln = lane & 15, quad = lane >> 4;
  const int wr = wave >> 1, wc = wave & 1;
  const int m0 = blockIdx.x * 128, n0 = blockIdx.y * 128;
  const char* Bb = (const char*)Bt;
  f32x4 acc[4][4] = {};
  const u16* Ap[4];
  #pragma unroll
  for (int i = 0; i < 4; ++i)
    Ap[i] = A + (size_t)(m0 + wr * 64 + i * 16 + ln) * 1024 + quad * 8;

  for (int k0 = 0; k0 < 1024; k0 += 64) {
    __syncthreads();
    #pragma unroll
    for (int it = 0; it < 4; ++it) {     // B tile: 128x64 = 1024 chunks, swizzled
      int c = it * 256 + t;
      int row = c >> 3, sg = (c & 7) ^ (row & 7);
      glds16(Bb + ((size_t)(n0 + row) * 1024 + k0 + sg * 8) * 2, (char*)Bl + c * 16);
    }
    bf16x8 a[4][2];                      // A: per-wave-exclusive rows, direct b128 loads
    #pragma unroll
    for (int i = 0; i < 4; ++i)
      #pragma unroll
      for (int ki = 0; ki < 2; ++ki)
        a[i][ki] = ld8(Ap[i] + k0 + ki * 32);
    __syncthreads();
    bf16x8 b[4][2];
    #pragma unroll
    for (int j = 0; j < 4; ++j) {
      const int row = wc * 64 + j * 16 + ln;
      #pragma unroll
      for (int ki = 0; ki < 2; ++ki)
        b[j][ki] = ld8(Bl + row * 64 + (((ki * 4 + quad) ^ (row & 7)) << 3));
    }
    #pragma unroll
    for (int i = 0; i < 4; ++i)
      #pragma unroll
      for (int j = 0; j < 4; ++j) {
        acc[i][j] = mfma16(a[i][0], b[j][0], acc[i][j]);
        acc[i][j] = mfma16(a[i][1], b[j][1], acc[i][j]);
      }
  }

  const int which = n0 >> 10;                    // 0=Q 1=K 2=V, block-uniform
  if (which < 2) {                               // RoPE fused, scatter [bh][s][64]
    u16* dst = which ? Ko : Qo;
    const float qs = which ? 1.0f : 0.18033688011112042f;  // log2(e)/8 on Q
    #pragma unroll
    for (int i = 0; i < 4; ++i) {
      const int mb = m0 + wr * 64 + i * 16 + quad * 4;     // r=0..3 stay in same s-run
      const int s0 = mb & 2047, b_ = mb >> 11;
      #pragma unroll
      for (int j = 0; j < 4; ++j) {
        const int c = n0 + wc * 64 + j * 16 + ln;
        const int h = (c >> 6) & 15, d = c & 63;
        const float sgn = (d & 1) ? 1.0f : -1.0f;
        const float4* csp = (const float4*)(cs + ((size_t)d * 2048 + s0) * 2);
        const float4 c01 = csp[0], c23 = csp[1];
        const float cosv[4] = {c01.x, c01.z, c23.x, c23.z};
        const float sinv[4] = {c01.y, c01.w, c23.y, c23.w};
        u16* drow = dst + ((size_t)(b_ * NH + h) * S_LEN + s0) * 64 + d;
        #pragma unroll
        for (int r = 0; r < 4; ++r) {
          const float v = acc[i][j][r];
          const float p = __shfl_xor(v, 1);      // rotate-half partner (d^1)
          drow[r * 64] = f2b((v * cosv[r] + sgn * p * sinv[r]) * qs);
        }
      }
    }
  } else {                                       // V: b64 scatter into Vt [bh][64][2048]
    #pragma unroll
    for (int i = 0; i < 4; ++i)
      #pragma unroll
      for (int j = 0; j < 4; ++j) {
        const int c = n0 + wc * 64 + j * 16 + ln;
        const int h = (c >> 6) & 15, d = c & 63;
        const int m = m0 + wr * 64 + i * 16 + quad * 4;
        const int s = m & 2047, b_ = m >> 11;
        u16 pk[4];
        #pragma unroll
        for (int r = 0; r < 4; ++r) pk[r] = f2b(acc[i][j][r]);
        *(uint2*)&Vt[((size_t)(b_ * NH + h) * 64 + d) * S_LEN + s] = *(const uint2*)pk;
      }
  }
}

// ---------- flash attention, S^T/O^T formulation (R8-verbatim, validated) ----------
// Q,K: [bh][2048][64] (Q pre-scaled), Vt: [bh][64][2048]; Ao: [4096][1024] bf16
__global__ __launch_bounds__(256) void attn_kernel(const u16* __restrict__ Qb,
                                                   const u16* __restrict__ Kb,
                                                   const u16* __restrict__ Vt,
                                                   u16* __restrict__ Ao) {
  __shared__ u16 smem[20480];          // Kl 2x4096 | Vl 2x4096 | Pl 4x1024 = 40960 B
  u16* Kl = smem;
  u16* Vl = smem + 8192;
  u16* Pl = smem + 16384;
  const int t = threadIdx.x;
  const int lane = t & 63, w = t >> 6;
  const int ln = lane & 15, quad = lane >> 4;
  // block decode: xcd-local bh (L2 reuse), per-CU-balanced qt
  const int i = blockIdx.x;
  const int xcd = i & 7;
  const int j = i >> 3;                  // 0..127
  const int bh = (xcd << 2) | (j & 3);   // 4 bh per XCD -> K/V L2-resident
  const int q5 = j >> 2;                 // 0..31
  const int g = q5 & 7, s5 = q5 >> 3;
  const int qt = (s5 & 1) ? (31 - ((s5 >> 1) << 3) - g) : (((s5 >> 1) << 3) + g);
  const int q0 = qt * 64;
  const int b = bh >> 4, h = bh & 15;
  const u16* Qbh = Qb + (size_t)bh * (S_LEN * 64);
  const u16* Kbh = Kb + (size_t)bh * (S_LEN * 64);
  const u16* Vtbh = Vt + (size_t)bh * (64 * S_LEN);
  u16* Plw = Pl + w * 1024;              // per-wave [16 q][64 t], 8-chunk XOR swizzled
  u16* AoBase = Ao + (size_t)b * S_LEN * DM + h * 64;

  auto stage = [&](int kt, int bufi) {
    u16* kd = Kl + bufi * 4096;
    u16* vd = Vl + bufi * 4096;
    const u16* kg = Kbh + (size_t)kt * 64 * 64;
    const u16* vg = Vtbh + (size_t)kt * 64;
    #pragma unroll
    for (int it = 0; it < 2; ++it) {
      int c = it * 256 + t;
      int row = c >> 3, sg = (c & 7) ^ (row & 7);
      glds16((const char*)kg + ((size_t)row * 64 + sg * 8) * 2,   (char*)kd + c * 16);
      glds16((const char*)vg + ((size_t)row * 2048 + sg * 8) * 2, (char*)vd + c * 16);
    }
  };

  // Q as B-fragment: n = this wave's 16 q rows
  bf16x8 bq[2];
  #pragma unroll
  for (int kk = 0; kk < 2; ++kk)
    bq[kk] = ld8(Qbh + (size_t)(q0 + w * 16 + ln) * 64 + kk * 32 + quad * 8);

  f32x4 o[4] = {};                       // O^T tiles: m=d (4 tiles), n=q
  float l = 0.f;                         // per-lane partial sum for q=ln over this quad's t

  stage(0, 0);
  __syncthreads();

  for (int kt = 0; kt <= qt; ++kt) {
    const int bufi = kt & 1;
    if (kt < qt) stage(kt + 1, bufi ^ 1);   // prefetch overlaps compute
    const u16* Kb_ = Kl + bufi * 4096;
    const u16* Vb_ = Vl + bufi * 4096;

    // S^T = K Q^T: A=K (m=t), B=Q (n=q)
    f32x4 st[4] = {};
    #pragma unroll
    for (int kk = 0; kk < 2; ++kk)
      #pragma unroll
      for (int ct = 0; ct < 4; ++ct) {
        bf16x8 ak = ld8(Kb_ + (ct * 16 + ln) * 64 + (((kk * 4 + quad) ^ (ln & 7)) << 3));
        st[ct] = mfma16(ak, bq[kk], st[ct]);
      }

    // exp2 + causal mask + l accumulate + P store (b64, swizzled)
    const bool diag = (kt == qt);
    #pragma unroll
    for (int ct = 0; ct < 4; ++ct) {
      u16 pk[4];
      #pragma unroll
      for (int r = 0; r < 4; ++r) {
        float p;
        if (diag && (ct * 16 + quad * 4 + r) > (w * 16 + ln)) p = 0.f;
        else p = __builtin_amdgcn_exp2f(st[ct][r]);
        l += p;
        pk[r] = f2b_trunc(p);
      }
      *(uint2*)(Plw + ln * 64 + ((((ct * 2) + (quad >> 1)) ^ (ln & 7)) << 3)
                + ((quad & 1) << 2)) = *(const uint2*)pk;
    }

    // O^T += Vt P^T: A=Vt (m=d), B=P (n=q)
    #pragma unroll
    for (int k4 = 0; k4 < 2; ++k4) {
      bf16x8 bp = ld8(Plw + ln * 64 + (((k4 * 4 + quad) ^ (ln & 7)) << 3));
      #pragma unroll
      for (int dt = 0; dt < 4; ++dt) {
        bf16x8 av = ld8(Vb_ + (dt * 16 + ln) * 64 + (((k4 * 4 + quad) ^ (ln & 7)) << 3));
        o[dt] = mfma16(av, bp, o[dt]);
      }
    }
    __syncthreads();                         // buf consumed; prefetch drained
  }

  // l: sum across the 4 quads holding q=ln
  l += __shfl_xor(l, 16);
  l += __shfl_xor(l, 32);
  const float inv = 1.f / l;
  const size_t qrow = (size_t)(q0 + w * 16 + ln) * DM;
  #pragma unroll
  for (int dt = 0; dt < 4; ++dt) {
    u16 pk[4];
    #pragma unroll
    for (int r = 0; r < 4; ++r) pk[r] = f2b(o[dt][r] * inv);
    *(uint2*)(AoBase + qrow + dt * 16 + quad * 4) = *(const uint2*)pk;
  }
}

// ---------- out-projection GEMM, R6-validated template form (TM x 128) ----------
template <int TM>
__global__ __launch_bounds__(256) void gemm_out_t(const u16* __restrict__ A,
                                                  const u16* __restrict__ Bt,
                                                  void* __restrict__ Out,
                                                  const int* __restrict__ flag) {
  constexpr int MI = TM / 32;
  __shared__ u16 smem[(TM + 128) * 32];
  u16* Al = smem;
  u16* Bl = smem + TM * 32;
  const int t = threadIdx.x;
  const int lane = t & 63, wave = t >> 6;
  const int ln = lane & 15, quad = lane >> 4;
  const int wr = wave >> 1, wc = wave & 1;
  const int m0 = blockIdx.x * TM, n0 = blockIdx.y * 128;
  const int rr = t >> 2;
  const int cb = (t & 3) * 16;
  const char* Ab = (const char*)A;
  const char* Bb = (const char*)Bt;
  f32x4 acc[MI][4] = {};

  for (int k0 = 0; k0 < 1024; k0 += 32) {
    __syncthreads();
    #pragma unroll
    for (int p = 0; p < TM / 64; ++p)
      glds16(Ab + ((size_t)(m0 + p * 64 + rr) * 1024 + k0) * 2 + cb,
             (char*)Al + p * 4096 + t * 16);
    glds16(Bb + ((size_t)(n0 + rr) * 1024 + k0) * 2 + cb,      (char*)Bl + t * 16);
    glds16(Bb + ((size_t)(n0 + 64 + rr) * 1024 + k0) * 2 + cb, (char*)Bl + 4096 + t * 16);
    __syncthreads();
    bf16x8 a[MI], b[4];
    #pragma unroll
    for (int i = 0; i < MI; ++i)
      a[i] = ld8(Al + (wr * (TM / 2) + i * 16 + ln) * 32 + quad * 8);
    #pragma unroll
    for (int j = 0; j < 4; ++j)
      b[j] = ld8(Bl + (wc * 64 + j * 16 + ln) * 32 + quad * 8);
    #pragma unroll
    for (int i = 0; i < MI; ++i)
      #pragma unroll
      for (int j = 0; j < 4; ++j)
        acc[i][j] = mfma16(a[i], b[j], acc[i][j]);
  }

  const int fl = *flag;
  #pragma unroll
  for (int i = 0; i < MI; ++i)
    #pragma unroll
    for (int j = 0; j < 4; ++j)
      #pragma unroll
      for (int r = 0; r < 4; ++r) {
        int m = m0 + wr * (TM / 2) + i * 16 + quad * 4 + r;
        int c = n0 + wc * 64 + j * 16 + ln;
        float v = acc[i][j][r];
        if (fl) ((u16*)Out)[(size_t)m * DM + c] = f2b(v);
        else    ((float*)Out)[(size_t)m * DM + c] = v;
      }
}

// ---------- launch ----------
extern "C" void kernel_launch(void* const* d_in, const int* in_sizes, int n_in,
                              void* d_out, int out_size, void* d_ws, size_t ws_size,
                              hipStream_t stream) {
  (void)in_sizes; (void)n_in; (void)out_size; (void)ws_size;
  const void* x    = d_in[0];
  const void* wqkv = d_in[2];
  const void* wout = d_in[3];
  char* ws = (char*)d_ws;
  u16*  xb   = (u16*)(ws + 0);            // 8 MB [4096][1024]; Ao aliases after gemm_qkv
  u16*  Ao   = xb;
  u16*  wqT  = (u16*)(ws + 8388608);      // 6 MB [3072][1024]
  u16*  woT  = (u16*)(ws + 14680064);     // 2 MB [1024][1024]
  u16*  Qb   = (u16*)(ws + 16777216);     // 8 MB [32][2048][64]
  u16*  Kb   = (u16*)(ws + 25165824);     // 8 MB
  u16*  Vt   = (u16*)(ws + 33554432);     // 8 MB [32][64][2048]
  float* cs  = (float*)(ws + 41943040);   // 1 MB [64 d][2048 s] float2 (cos,sin)
  int*  flag = (int*)(ws + 42991616);

  prep_kernel<<<3584, 256, 0, stream>>>(x, wqkv, wout, xb, wqT, woT, cs, flag);
  gemm_qkv<<<dim3(32, 24), 256, 0, stream>>>(xb, wqT, Qb, Kb, Vt, cs);
  attn_kernel<<<1024, 256, 0, stream>>>(Qb, Kb, Vt, Ao);
  gemm_out_t<64><<<dim3(64, 8), 256, 0, stream>>>(Ao, woT, d_out, flag);
}

// Round 10
// 189.862 us; speedup vs baseline: 1.1337x; 1.1337x over previous
//
#include <hip/hip_runtime.h>
#include <stdint.h>

typedef unsigned short u16;
typedef __bf16 bf16x8 __attribute__((ext_vector_type(8)));
typedef float f32x4 __attribute__((ext_vector_type(4)));

#define S_LEN 2048
#define NH    16
#define DM    1024
#define N3    3072
#define MROWS 4096   // B*S

// ---------- scalar bf16 helpers ----------
__device__ __forceinline__ float b2f(u16 u) {
  unsigned int v = ((unsigned int)u) << 16;
  return __builtin_bit_cast(float, v);
}
__device__ __forceinline__ u16 f2b(float f) {
  unsigned int v = __builtin_bit_cast(unsigned int, f);
  v += 0x7fffu + ((v >> 16) & 1u);   // RNE
  return (u16)(v >> 16);
}
__device__ __forceinline__ u16 f2b_trunc(float f) {
  return (u16)(__builtin_bit_cast(unsigned int, f) >> 16);
}
__device__ __forceinline__ bf16x8 ld8(const u16* p) { return *(const bf16x8*)p; }
__device__ __forceinline__ f32x4 mfma16(bf16x8 a, bf16x8 b, f32x4 c) {
  return __builtin_amdgcn_mfma_f32_16x16x32_bf16(a, b, c, 0, 0, 0);
}
__device__ __forceinline__ void glds16(const void* g, void* l) {
  __builtin_amdgcn_global_load_lds(
      (const __attribute__((address_space(1))) unsigned int*)g,
      (__attribute__((address_space(3))) unsigned int*)l, 16, 0, 0);
}
// bf16-vs-f32 word test: low-16 as bf16, exponent in [100,134]
__device__ __forceinline__ int bfish(unsigned int w) {
  unsigned int e = (w >> 7) & 0xffu;
  return (e >= 100u && e <= 134u) ? 1 : 0;
}

// ---------- fused prep: x->bf16 + cs table + both weight transposes + flag ----------
// blocks [0,2048): x conv | [2048,2560): cs table | [2560,3328): wqkv^T | [3328,3584): wout^T
__global__ __launch_bounds__(256) void prep_kernel(const void* __restrict__ x,
                                                   const void* __restrict__ wqkv,
                                                   const void* __restrict__ wout,
                                                   u16* __restrict__ xb,
                                                   u16* __restrict__ wqT,
                                                   u16* __restrict__ woT,
                                                   float* __restrict__ cs,
                                                   int* __restrict__ flag) {
  const int bx = blockIdx.x;
  const int t = threadIdx.x;
  if (bx < 2048) {                       // x -> bf16, self-detecting
    __shared__ int cnt;
    if (t == 0) cnt = 0;
    __syncthreads();
    size_t i = (size_t)bx * 256 + t;     // 524288 uint4 slots (safe both dtypes)
    const uint4* xv = (const uint4*)x;
    uint4 probe = xv[i];
    unsigned int wds[4]; *(uint4*)wds = probe;
    atomicAdd(&cnt, bfish(wds[0]) + bfish(wds[1]) + bfish(wds[2]) + bfish(wds[3]));
    __syncthreads();
    const int isbf = cnt > 512;
    if (t == 0) *flag = isbf;            // benign same-value race
    if (isbf) {
      ((uint4*)xb)[i] = probe;
    } else {
      const float* xf = (const float*)x;
      #pragma unroll
      for (int j = 0; j < 8; ++j) xb[i * 8 + j] = f2b(xf[i * 8 + j]);
    }
    return;
  }
  if (bx < 2560) {                       // cs table: [64 d][2048 s] interleaved (cos,sin)
    int i = (bx - 2048) * 256 + t;       // 131072 = 64*2048
    int d = i >> 11, s = i & 2047;
    int f = d & 31;                      // concat(freqs,freqs): inv_freq index = d mod 32
    float invf = expf(-(float)(2 * f) * (1.0f / 64.0f) * logf(10000.0f));
    float th = (float)s * invf;
    float sv, cv;
    sincosf(th, &sv, &cv);
    cs[i * 2] = cv; cs[i * 2 + 1] = sv;  // i*2 == (d*2048+s)*2
    return;
  }
  // weight transpose [R=1024][C] -> bf16 [C][1024], 64x64 tiles (V-transpose pattern)
  const int wq = bx < 3328;
  const int id = wq ? (bx - 2560) : (bx - 3328);
  const int ncx = wq ? 48 : 16;
  const void* in = wq ? wqkv : wout;
  u16* out = wq ? wqT : woT;
  const int C = wq ? 3072 : 1024;
  const int c0 = (id % ncx) * 64, r0 = (id / ncx) * 64;
  __shared__ int cnt;
  __shared__ u16 L[4096];                // [64 c][64 r], r-seg XOR swizzled
  if (t == 0) cnt = 0;
  __syncthreads();
  const unsigned int* wv = (const unsigned int*)in;
  size_t off = (((size_t)id) * 256 + t) & 262143;   // sample first 256K words (safe both)
  atomicAdd(&cnt, bfish(wv[off]));
  __syncthreads();
  const int fl = cnt > 128;
  if (fl) {                              // bf16: uint4 loads, unpack into swizzled LDS
    #pragma unroll
    for (int it = 0; it < 2; ++it) {
      int c = it * 256 + t;
      int rl = c >> 3, cseg = c & 7;
      uint4 v = *(const uint4*)((const u16*)in + (size_t)(r0 + rl) * C + c0 + cseg * 8);
      u16 e[8]; *(uint4*)e = v;
      #pragma unroll
      for (int jj = 0; jj < 8; ++jj) {
        int cl = cseg * 8 + jj;
        L[cl * 64 + (rl ^ (cseg << 3))] = e[jj];
      }
    }
  } else {                               // fp32 fallback: scalar convert
    const float* inf_ = (const float*)in;
    #pragma unroll
    for (int it = 0; it < 16; ++it) {
      int c = it * 256 + t;
      int rl = c >> 6, cl = c & 63;
      L[cl * 64 + (rl ^ ((cl >> 3) << 3))] = f2b(inf_[(size_t)(r0 + rl) * C + c0 + cl]);
    }
  }
  __syncthreads();
  #pragma unroll
  for (int it = 0; it < 2; ++it) {
    int c = it * 256 + t;
    int cl = c >> 3, rseg = c & 7;
    uint4 v = *(const uint4*)(L + cl * 64 + (((rseg ^ (cl >> 3)) & 7) << 3));
    *(uint4*)(out + (size_t)(c0 + cl) * 1024 + r0 + rseg * 8) = v;
  }
}

// ---------- QKV GEMM 128x128, BK=64, swizzled LDS (R8-verbatim K-loop) + cs-table epilogue ----------
// A: xb [4096][1024], Bt: wqT [3072][1024]
// Q,K -> [bh][2048][64] (Q pre-scaled by log2e/8); V -> Vt [bh][64][2048]
__global__ __launch_bounds__(256) void gemm_qkv(const u16* __restrict__ A,
                                                const u16* __restrict__ Bt,
                                                u16* __restrict__ Qo,
                                                u16* __restrict__ Ko,
                                                u16* __restrict__ Vt,
                                                const float* __restrict__ cs) {
  __shared__ u16 smem[16384];          // Al[128][64] | Bl[128][64] = 32 KB
  u16* Al = smem;
  u16* Bl = smem + 8192;
  const int t = threadIdx.x;
  const int lane = t & 63, wave = t >> 6;
  const int ln = lane & 15, quad = lane >> 4;
  const int wr = wave >> 1, wc = wave & 1;
  const int m0 = blockIdx.x * 128, n0 = blockIdx.y * 128;
  const char* Ab = (const char*)A;
  const char* Bb = (const char*)Bt;
  f32x4 acc[4][4] = {};

  for (int k0 = 0; k0 < 1024; k0 += 64) {
    __syncthreads();
    // stage 128x64 tiles; row chunk j stored at LDS chunk j^(row&7)
    #pragma unroll
    for (int it = 0; it < 4; ++it) {
      int c = it * 256 + t;              // 1024 chunks of 16B per matrix
      int row = c >> 3;
      int sg = (c & 7) ^ (row & 7);      // source chunk for this LDS slot
      glds16(Ab + ((size_t)(m0 + row) * 1024 + k0 + sg * 8) * 2, (char*)Al + c * 16);
      glds16(Bb + ((size_t)(n0 + row) * 1024 + k0 + sg * 8) * 2, (char*)Bl + c * 16);
    }
    __syncthreads();
    bf16x8 a[4][2], b[4][2];
    #pragma unroll
    for (int i = 0; i < 4; ++i) {
      const int row = wr * 64 + i * 16 + ln;
      #pragma unroll
      for (int ki = 0; ki < 2; ++ki)
        a[i][ki] = ld8(Al + row * 64 + (((ki * 4 + quad) ^ (row & 7)) << 3));
    }
    #pragma unroll
    for (int j = 0; j < 4; ++j) {
      const int row = wc * 64 + j * 16 + ln;
      #pragma unroll
      for (int ki = 0; ki < 2; ++ki)
        b[j][ki] = ld8(Bl + row * 64 + (((ki * 4 + quad) ^ (row & 7)) << 3));
    }
    #pragma unroll
    for (int i = 0; i < 4; ++i)
      #pragma unroll
      for (int j = 0; j < 4; ++j) {
        acc[i][j] = mfma16(a[i][0], b[j][0], acc[i][j]);
        acc[i][j] = mfma16(a[i][1], b[j][1], acc[i][j]);
      }
  }

  const int which = n0 >> 10;                    // 0=Q 1=K 2=V, block-uniform
  if (which < 2) {                               // RoPE fused, scatter [bh][s][64]
    u16* dst = which ? Ko : Qo;
    const float qs = which ? 1.0f : 0.18033688011112042f;  // log2(e)/8 on Q
    #pragma unroll
    for (int i = 0; i < 4; ++i) {
      const int mb = m0 + wr * 64 + i * 16 + quad * 4;     // r=0..3 stay in same s-run
      const int s0 = mb & 2047, b_ = mb >> 11;
      #pragma unroll
      for (int j = 0; j < 4; ++j) {
        const int c = n0 + wc * 64 + j * 16 + ln;
        const int h = (c >> 6) & 15, d = c & 63;
        const float sgn = (d & 1) ? 1.0f : -1.0f;
        const float4* csp = (const float4*)(cs + ((size_t)d * 2048 + s0) * 2);
        const float4 c01 = csp[0], c23 = csp[1];
        const float cosv[4] = {c01.x, c01.z, c23.x, c23.z};
        const float sinv[4] = {c01.y, c01.w, c23.y, c23.w};
        u16* drow = dst + ((size_t)(b_ * NH + h) * S_LEN + s0) * 64 + d;
        #pragma unroll
        for (int r = 0; r < 4; ++r) {
          const float v = acc[i][j][r];
          const float p = __shfl_xor(v, 1);      // rotate-half partner (d^1)
          drow[r * 64] = f2b((v * cosv[r] + sgn * p * sinv[r]) * qs);
        }
      }
    }
  } else {                                       // V: b64 scatter into Vt [bh][64][2048]
    #pragma unroll
    for (int i = 0; i < 4; ++i)
      #pragma unroll
      for (int j = 0; j < 4; ++j) {
        const int c = n0 + wc * 64 + j * 16 + ln;
        const int h = (c >> 6) & 15, d = c & 63;
        const int m = m0 + wr * 64 + i * 16 + quad * 4;
        const int s = m & 2047, b_ = m >> 11;
        u16 pk[4];
        #pragma unroll
        for (int r = 0; r < 4; ++r) pk[r] = f2b(acc[i][j][r]);
        *(uint2*)&Vt[((size_t)(b_ * NH + h) * 64 + d) * S_LEN + s] = *(const uint2*)pk;
      }
  }
}

// ---------- flash attention, S^T/O^T formulation (R8-verbatim, validated) ----------
// Q,K: [bh][2048][64] (Q pre-scaled), Vt: [bh][64][2048]; Ao: [4096][1024] bf16
__global__ __launch_bounds__(256) void attn_kernel(const u16* __restrict__ Qb,
                                                   const u16* __restrict__ Kb,
                                                   const u16* __restrict__ Vt,
                                                   u16* __restrict__ Ao) {
  __shared__ u16 smem[20480];          // Kl 2x4096 | Vl 2x4096 | Pl 4x1024 = 40960 B
  u16* Kl = smem;
  u16* Vl = smem + 8192;
  u16* Pl = smem + 16384;
  const int t = threadIdx.x;
  const int lane = t & 63, w = t >> 6;
  const int ln = lane & 15, quad = lane >> 4;
  // block decode: xcd-local bh (L2 reuse), per-CU-balanced qt
  const int i = blockIdx.x;
  const int xcd = i & 7;
  const int j = i >> 3;                  // 0..127
  const int bh = (xcd << 2) | (j & 3);   // 4 bh per XCD -> K/V L2-resident
  const int q5 = j >> 2;                 // 0..31
  const int g = q5 & 7, s5 = q5 >> 3;
  const int qt = (s5 & 1) ? (31 - ((s5 >> 1) << 3) - g) : (((s5 >> 1) << 3) + g);
  const int q0 = qt * 64;
  const int b = bh >> 4, h = bh & 15;
  const u16* Qbh = Qb + (size_t)bh * (S_LEN * 64);
  const u16* Kbh = Kb + (size_t)bh * (S_LEN * 64);
  const u16* Vtbh = Vt + (size_t)bh * (64 * S_LEN);
  u16* Plw = Pl + w * 1024;              // per-wave [16 q][64 t], 8-chunk XOR swizzled
  u16* AoBase = Ao + (size_t)b * S_LEN * DM + h * 64;

  auto stage = [&](int kt, int bufi) {
    u16* kd = Kl + bufi * 4096;
    u16* vd = Vl + bufi * 4096;
    const u16* kg = Kbh + (size_t)kt * 64 * 64;
    const u16* vg = Vtbh + (size_t)kt * 64;
    #pragma unroll
    for (int it = 0; it < 2; ++it) {
      int c = it * 256 + t;
      int row = c >> 3, sg = (c & 7) ^ (row & 7);
      glds16((const char*)kg + ((size_t)row * 64 + sg * 8) * 2,   (char*)kd + c * 16);
      glds16((const char*)vg + ((size_t)row * 2048 + sg * 8) * 2, (char*)vd + c * 16);
    }
  };

  // Q as B-fragment: n = this wave's 16 q rows
  bf16x8 bq[2];
  #pragma unroll
  for (int kk = 0; kk < 2; ++kk)
    bq[kk] = ld8(Qbh + (size_t)(q0 + w * 16 + ln) * 64 + kk * 32 + quad * 8);

  f32x4 o[4] = {};                       // O^T tiles: m=d (4 tiles), n=q
  float l = 0.f;                         // per-lane partial sum for q=ln over this quad's t

  stage(0, 0);
  __syncthreads();

  for (int kt = 0; kt <= qt; ++kt) {
    const int bufi = kt & 1;
    if (kt < qt) stage(kt + 1, bufi ^ 1);   // prefetch overlaps compute
    const u16* Kb_ = Kl + bufi * 4096;
    const u16* Vb_ = Vl + bufi * 4096;

    // S^T = K Q^T: A=K (m=t), B=Q (n=q)
    f32x4 st[4] = {};
    #pragma unroll
    for (int kk = 0; kk < 2; ++kk)
      #pragma unroll
      for (int ct = 0; ct < 4; ++ct) {
        bf16x8 ak = ld8(Kb_ + (ct * 16 + ln) * 64 + (((kk * 4 + quad) ^ (ln & 7)) << 3));
        st[ct] = mfma16(ak, bq[kk], st[ct]);
      }

    // exp2 + causal mask + l accumulate + P store (b64, swizzled)
    const bool diag = (kt == qt);
    #pragma unroll
    for (int ct = 0; ct < 4; ++ct) {
      u16 pk[4];
      #pragma unroll
      for (int r = 0; r < 4; ++r) {
        float p;
        if (diag && (ct * 16 + quad * 4 + r) > (w * 16 + ln)) p = 0.f;
        else p = __builtin_amdgcn_exp2f(st[ct][r]);
        l += p;
        pk[r] = f2b_trunc(p);
      }
      *(uint2*)(Plw + ln * 64 + ((((ct * 2) + (quad >> 1)) ^ (ln & 7)) << 3)
                + ((quad & 1) << 2)) = *(const uint2*)pk;
    }

    // O^T += Vt P^T: A=Vt (m=d), B=P (n=q)
    #pragma unroll
    for (int k4 = 0; k4 < 2; ++k4) {
      bf16x8 bp = ld8(Plw + ln * 64 + (((k4 * 4 + quad) ^ (ln & 7)) << 3));
      #pragma unroll
      for (int dt = 0; dt < 4; ++dt) {
        bf16x8 av = ld8(Vb_ + (dt * 16 + ln) * 64 + (((k4 * 4 + quad) ^ (ln & 7)) << 3));
        o[dt] = mfma16(av, bp, o[dt]);
      }
    }
    __syncthreads();                         // buf consumed; prefetch drained
  }

  // l: sum across the 4 quads holding q=ln
  l += __shfl_xor(l, 16);
  l += __shfl_xor(l, 32);
  const float inv = 1.f / l;
  const size_t qrow = (size_t)(q0 + w * 16 + ln) * DM;
  #pragma unroll
  for (int dt = 0; dt < 4; ++dt) {
    u16 pk[4];
    #pragma unroll
    for (int r = 0; r < 4; ++r) pk[r] = f2b(o[dt][r] * inv);
    *(uint2*)(AoBase + qrow + dt * 16 + quad * 4) = *(const uint2*)pk;
  }
}

// ---------- out-projection GEMM, R6-validated template form (TM x 128) ----------
template <int TM>
__global__ __launch_bounds__(256) void gemm_out_t(const u16* __restrict__ A,
                                                  const u16* __restrict__ Bt,
                                                  void* __restrict__ Out,
                                                  const int* __restrict__ flag) {
  constexpr int MI = TM / 32;
  __shared__ u16 smem[(TM + 128) * 32];
  u16* Al = smem;
  u16* Bl = smem + TM * 32;
  const int t = threadIdx.x;
  const int lane = t & 63, wave = t >> 6;
  const int ln = lane & 15, quad = lane >> 4;
  const int wr = wave >> 1, wc = wave & 1;
  const int m0 = blockIdx.x * TM, n0 = blockIdx.y * 128;
  const int rr = t >> 2;
  const int cb = (t & 3) * 16;
  const char* Ab = (const char*)A;
  const char* Bb = (const char*)Bt;
  f32x4 acc[MI][4] = {};

  for (int k0 = 0; k0 < 1024; k0 += 32) {
    __syncthreads();
    #pragma unroll
    for (int p = 0; p < TM / 64; ++p)
      glds16(Ab + ((size_t)(m0 + p * 64 + rr) * 1024 + k0) * 2 + cb,
             (char*)Al + p * 4096 + t * 16);
    glds16(Bb + ((size_t)(n0 + rr) * 1024 + k0) * 2 + cb,      (char*)Bl + t * 16);
    glds16(Bb + ((size_t)(n0 + 64 + rr) * 1024 + k0) * 2 + cb, (char*)Bl + 4096 + t * 16);
    __syncthreads();
    bf16x8 a[MI], b[4];
    #pragma unroll
    for (int i = 0; i < MI; ++i)
      a[i] = ld8(Al + (wr * (TM / 2) + i * 16 + ln) * 32 + quad * 8);
    #pragma unroll
    for (int j = 0; j < 4; ++j)
      b[j] = ld8(Bl + (wc * 64 + j * 16 + ln) * 32 + quad * 8);
    #pragma unroll
    for (int i = 0; i < MI; ++i)
      #pragma unroll
      for (int j = 0; j < 4; ++j)
        acc[i][j] = mfma16(a[i], b[j], acc[i][j]);
  }

  const int fl = *flag;
  #pragma unroll
  for (int i = 0; i < MI; ++i)
    #pragma unroll
    for (int j = 0; j < 4; ++j)
      #pragma unroll
      for (int r = 0; r < 4; ++r) {
        int m = m0 + wr * (TM / 2) + i * 16 + quad * 4 + r;
        int c = n0 + wc * 64 + j * 16 + ln;
        float v = acc[i][j][r];
        if (fl) ((u16*)Out)[(size_t)m * DM + c] = f2b(v);
        else    ((float*)Out)[(size_t)m * DM + c] = v;
      }
}

// ---------- launch ----------
extern "C" void kernel_launch(void* const* d_in, const int* in_sizes, int n_in,
                              void* d_out, int out_size, void* d_ws, size_t ws_size,
                              hipStream_t stream) {
  (void)in_sizes; (void)n_in; (void)out_size; (void)ws_size;
  const void* x    = d_in[0];
  const void* wqkv = d_in[2];
  const void* wout = d_in[3];
  char* ws = (char*)d_ws;
  u16*  xb   = (u16*)(ws + 0);            // 8 MB [4096][1024]; Ao aliases after gemm_qkv
  u16*  Ao   = xb;
  u16*  wqT  = (u16*)(ws + 8388608);      // 6 MB [3072][1024]
  u16*  woT  = (u16*)(ws + 14680064);     // 2 MB [1024][1024]
  u16*  Qb   = (u16*)(ws + 16777216);     // 8 MB [32][2048][64]
  u16*  Kb   = (u16*)(ws + 25165824);     // 8 MB
  u16*  Vt   = (u16*)(ws + 33554432);     // 8 MB [32][64][2048]
  float* cs  = (float*)(ws + 41943040);   // 1 MB [64 d][2048 s] float2 (cos,sin)
  int*  flag = (int*)(ws + 42991616);

  prep_kernel<<<3584, 256, 0, stream>>>(x, wqkv, wout, xb, wqT, woT, cs, flag);
  gemm_qkv<<<dim3(32, 24), 256, 0, stream>>>(xb, wqT, Qb, Kb, Vt, cs);
  attn_kernel<<<1024, 256, 0, stream>>>(Qb, Kb, Vt, Ao);
  gemm_out_t<64><<<dim3(64, 8), 256, 0, stream>>>(Ao, woT, d_out, flag);
}